// Round 16
// baseline (83.523 us; speedup 1.0000x reference)
//
#include <hip/hip_runtime.h>
#include <hip/hip_bf16.h>
#include <hip/hip_fp16.h>

#define NN 50000
#define NE 800000
#define EPS 1e-5f
#define NW 782            // ceil(NN/64) windows of 64 nodes
#define CAP 2560          // fixed per-window colw slots (max window load ~1150)
#define WFB 200           // wfill blocks
#define CHUNK (NE / WFB)  // 4000 edges per wfill block
#define PREPB 64          // prep blocks
#define INPB ((NN + 31) / 32)

typedef _Float16 f16;
typedef _Float16 f16x8 __attribute__((ext_vector_type(8)));
typedef float f32x4 __attribute__((ext_vector_type(4)));

#define F2ADD(a, b) { (a).x += (b).x; (a).y += (b).y; }

__device__ __forceinline__ int waveInclScan(int v, int lane) {
#pragma unroll
    for (int o = 1; o < 64; o <<= 1) {
        int t = __shfl_up(v, o, 64);
        if (lane >= o) v += t;
    }
    return v;
}

// ---------------- prep: weight transposes + wcur init ----------------
__global__ __launch_bounds__(256) void k_prep_init(const float* __restrict__ Win,
                                                   const float* __restrict__ Wl,
                                                   const float* __restrict__ Wr,
                                                   const float* __restrict__ Wl2,
                                                   const float* __restrict__ Wr2,
                                                   const float* __restrict__ Wo1,
                                                   f16* __restrict__ WinT,
                                                   f16* __restrict__ W2T,
                                                   f16* __restrict__ W3T,
                                                   f16* __restrict__ Wo1T,
                                                   int* __restrict__ wcur) {
    int i0 = blockIdx.x * 256 + threadIdx.x;
    for (int i = i0; i < 128 * 104; i += PREPB * 256) {
        int c = i / 104, k = i - c * 104;
        float v = (k < 84) ? Win[k * 128 + c] : 0.f;
        WinT[c * 104 + k] = (f16)v;
    }
    for (int i = i0; i < 128 * 136; i += PREPB * 256) {
        int c = i / 136, k = i - c * 136;
        float v = 0.f;
        if (k < 128) v = (c < 64) ? Wl[k * 64 + c] : Wr[k * 64 + (c - 64)];
        W2T[c * 136 + k] = (f16)v;
    }
    for (int i = i0; i < 64 * 72; i += PREPB * 256) {
        int c = i / 72, k = i - c * 72;
        float v = 0.f;
        if (k < 64) v = (c < 32) ? Wl2[k * 32 + c] : Wr2[k * 32 + (c - 32)];
        W3T[c * 72 + k] = (f16)v;
    }
    for (int i = i0; i < 16 * 40; i += PREPB * 256) {
        int c = i / 40, k = i - c * 40;
        float v = (k < 32) ? Wo1[k * 16 + c] : 0.f;
        Wo1T[c * 40 + k] = (f16)v;
    }
    for (int i = i0; i < NW; i += PREPB * 256) wcur[i] = i * CAP;
}

// ---------------- fused: wfill (blocks <WFB) | MFMA in_proj1 (rest) ----------------
__global__ __launch_bounds__(256) void k_wfill_inproj(const int* __restrict__ src,
                                                      const int* __restrict__ tgt,
                                                      int* __restrict__ wcur,
                                                      int* __restrict__ colw,
                                                      const float* __restrict__ x,
                                                      const f16* __restrict__ WinT,
                                                      const float* __restrict__ bin,
                                                      const f16* __restrict__ W2T,
                                                      const float* __restrict__ bl,
                                                      f16* __restrict__ p1h,
                                                      f16* __restrict__ r1h, int N) {
    __shared__ int lh[NW];
    __shared__ int sb[NW];
    __shared__ __align__(16) f16 xs[32 * 104];
    __shared__ __align__(16) f16 hs[32 * 136];
    int tid = threadIdx.x;

    if (blockIdx.x < WFB) {
        // span-reserved window partition into CAP-strided colw
        int i4lo = (blockIdx.x * CHUNK) >> 2;
        int i4hi = i4lo + (CHUNK >> 2);
        for (int i = tid; i < NW; i += 256) lh[i] = 0;
        __syncthreads();
        for (int i4 = i4lo + tid; i4 < i4hi; i4 += 256) {
            int4 t = ((const int4*)tgt)[i4];
            atomicAdd(&lh[t.x >> 6], 1);
            atomicAdd(&lh[t.y >> 6], 1);
            atomicAdd(&lh[t.z >> 6], 1);
            atomicAdd(&lh[t.w >> 6], 1);
        }
        __syncthreads();
        for (int i = tid; i < NW; i += 256) {
            int c = lh[i];
            sb[i] = c ? atomicAdd(&wcur[i], c) : 0;
            lh[i] = 0;
        }
        __syncthreads();
        for (int i4 = i4lo + tid; i4 < i4hi; i4 += 256) {
            int4 t = ((const int4*)tgt)[i4];
            int4 s = ((const int4*)src)[i4];
            int w0 = t.x >> 6, r0 = atomicAdd(&lh[w0], 1);
            colw[sb[w0] + r0] = (s.x << 6) | (t.x & 63);
            int w1 = t.y >> 6, r1 = atomicAdd(&lh[w1], 1);
            colw[sb[w1] + r1] = (s.y << 6) | (t.y & 63);
            int w2 = t.z >> 6, r2 = atomicAdd(&lh[w2], 1);
            colw[sb[w2] + r2] = (s.z << 6) | (t.z & 63);
            int w3 = t.w >> 6, r3 = atomicAdd(&lh[w3], 1);
            colw[sb[w3] + r3] = (s.w << 6) | (t.w & 63);
        }
        return;
    }

    // ---- in_proj1: x -> h1 (LDS) -> p1, r1 via MFMA ----
    int node0 = (blockIdx.x - WFB) * 32;
    int lane = tid & 63;
    int wv = tid >> 6;
    int r = lane & 15;
    int q = lane >> 4;

    f16x8 b1[2][3];
#pragma unroll
    for (int nt = 0; nt < 2; nt++) {
        int c = (2 * wv + nt) * 16 + r;
#pragma unroll
        for (int ks = 0; ks < 3; ks++)
            b1[nt][ks] = *(const f16x8*)&WinT[c * 104 + ks * 32 + q * 8];
    }
    // float4-vectorized x staging
    for (int i = tid; i < 672; i += 256) {
        int nd = i / 21, k4 = i - nd * 21;
        int g = node0 + nd;
        float4 v = make_float4(0.f, 0.f, 0.f, 0.f);
        if (g < N) v = ((const float4*)x)[(size_t)g * 21 + k4];
        f16* dst = &xs[nd * 104 + k4 * 4];
        dst[0] = (f16)v.x; dst[1] = (f16)v.y; dst[2] = (f16)v.z; dst[3] = (f16)v.w;
    }
    for (int i = tid; i < 32 * 12; i += 256) {
        int nd = i / 12, k = 84 + (i - nd * 12);
        xs[nd * 104 + k] = (f16)0.f;
    }
    __syncthreads();

    f32x4 acc[2][2] = {};
#pragma unroll
    for (int ks = 0; ks < 3; ks++) {
        int k0 = ks * 32;
        f16x8 a[2];
#pragma unroll
        for (int mt = 0; mt < 2; mt++)
            a[mt] = *(const f16x8*)&xs[(mt * 16 + r) * 104 + k0 + q * 8];
#pragma unroll
        for (int mt = 0; mt < 2; mt++)
#pragma unroll
            for (int nt = 0; nt < 2; nt++)
                acc[mt][nt] = __builtin_amdgcn_mfma_f32_16x16x32_f16(a[mt], b1[nt][ks], acc[mt][nt], 0, 0, 0);
    }

    f16x8 b2[2][4];
#pragma unroll
    for (int nt = 0; nt < 2; nt++) {
        int c = (2 * wv + nt) * 16 + r;
#pragma unroll
        for (int ks = 0; ks < 4; ks++)
            b2[nt][ks] = *(const f16x8*)&W2T[c * 136 + ks * 32 + q * 8];
    }

#pragma unroll
    for (int nt = 0; nt < 2; nt++) {
        int c = (2 * wv + nt) * 16 + r;
        float bb = bin[c];
#pragma unroll
        for (int mt = 0; mt < 2; mt++)
#pragma unroll
            for (int v = 0; v < 4; v++) {
                int row = mt * 16 + q * 4 + v;
                float val = acc[mt][nt][v] + bb;
                hs[row * 136 + c] = (f16)(val > 0.f ? val : 0.f);
            }
    }
    __syncthreads();

    f32x4 acc2[2][2] = {};
#pragma unroll
    for (int ks = 0; ks < 4; ks++) {
        int k0 = ks * 32;
        f16x8 a[2];
#pragma unroll
        for (int mt = 0; mt < 2; mt++)
            a[mt] = *(const f16x8*)&hs[(mt * 16 + r) * 136 + k0 + q * 8];
#pragma unroll
        for (int mt = 0; mt < 2; mt++)
#pragma unroll
            for (int nt = 0; nt < 2; nt++)
                acc2[mt][nt] = __builtin_amdgcn_mfma_f32_16x16x32_f16(a[mt], b2[nt][ks], acc2[mt][nt], 0, 0, 0);
    }

    // epilogue 2: repack into hs (dead after GEMM2), then coalesced f16x8 stores
    __syncthreads();
#pragma unroll
    for (int nt = 0; nt < 2; nt++) {
        int c = (2 * wv + nt) * 16 + r;
        float bb = (c >= 64) ? bl[c - 64] : 0.f;
#pragma unroll
        for (int mt = 0; mt < 2; mt++)
#pragma unroll
            for (int v = 0; v < 4; v++) {
                int row = mt * 16 + q * 4 + v;
                hs[row * 136 + c] = (f16)(acc2[mt][nt][v] + bb);
            }
    }
    __syncthreads();
    {
        int row = tid >> 3, c8 = tid & 7;   // 32 rows x 8 chunks
        int n = node0 + row;
        if (n < N) {
            f16x8 vp = *(const f16x8*)&hs[row * 136 + c8 * 8];
            *(f16x8*)&p1h[(size_t)n * 64 + c8 * 8] = vp;
            f16x8 vr = *(const f16x8*)&hs[row * 136 + 64 + c8 * 8];
            *(f16x8*)&r1h[(size_t)n * 64 + c8 * 8] = vr;
        }
    }
}

// masked dual-node gather step: 4 loads per node, 8 independent loads in flight
#define GATH4(pv, STRIDE, LANE, s0, len, i, A0, A1, A2, A3)                          \
    {                                                                                \
        int i0_ = i, i1_ = i + 1, i2_ = i + 2, i3_ = i + 3;                          \
        unsigned x0_ = (i0_ < len) ? (unsigned)sorted[s0 + i0_] : 0u;                \
        unsigned x1_ = (i1_ < len) ? (unsigned)sorted[s0 + i1_] : 0u;                \
        unsigned x2_ = (i2_ < len) ? (unsigned)sorted[s0 + i2_] : 0u;                \
        unsigned x3_ = (i3_ < len) ? (unsigned)sorted[s0 + i3_] : 0u;                \
        float m0_ = (i0_ < len) ? 1.f : 0.f;                                         \
        float m1_ = (i1_ < len) ? 1.f : 0.f;                                         \
        float m2_ = (i2_ < len) ? 1.f : 0.f;                                         \
        float m3_ = (i3_ < len) ? 1.f : 0.f;                                         \
        float2 v0_ = __half22float2(pv[x0_ * STRIDE + LANE]);                        \
        float2 v1_ = __half22float2(pv[x1_ * STRIDE + LANE]);                        \
        float2 v2_ = __half22float2(pv[x2_ * STRIDE + LANE]);                        \
        float2 v3_ = __half22float2(pv[x3_ * STRIDE + LANE]);                        \
        A0.x += m0_ * v0_.x; A0.y += m0_ * v0_.y;                                    \
        A1.x += m1_ * v1_.x; A1.y += m1_ * v1_.y;                                    \
        A2.x += m2_ * v2_.x; A2.y += m2_ * v2_.y;                                    \
        A3.x += m3_ * v3_.x; A3.y += m3_ * v3_.y;                                    \
    }

// ---------------- agg1 (per-window, one block): LDS sort -> paired gather+LN -> MFMA proj2 ----------------
__global__ __launch_bounds__(512) void k_agg1_proj2(const __half2* __restrict__ p1v,
                                                    const __half2* __restrict__ r1v,
                                                    const int* __restrict__ wcur,
                                                    const int* __restrict__ colw,
                                                    const float* __restrict__ g1,
                                                    const float* __restrict__ be1,
                                                    const f16* __restrict__ W3T,
                                                    const float* __restrict__ bl2,
                                                    f16* __restrict__ p2h,
                                                    f16* __restrict__ r2h, int N) {
    __shared__ int cnt[64], start[64], cur[64];
    __shared__ int sorted[CAP];
    __shared__ __align__(16) f16 ys[64][72];
    int tid = threadIdx.x;
    int wb = blockIdx.x;
    int base = wb * CAP;
    int nb = wb << 6;
    int len = wcur[wb] - base;
    if (len > CAP) len = CAP;

    unsigned cc = tid & 31;
    int grp = tid >> 5;       // 16 groups of 32 lanes
    int lane = tid & 63;
    int wv = tid >> 6;        // 8 waves
    int r = lane & 15;
    int q = lane >> 4;

    // proj2 B-fragments hoisted (overlaps with sort/gather latency)
    int mt = wv & 3;
    int ntbase = (wv >> 2) * 2;
    f16x8 b3[2][2];
#pragma unroll
    for (int j = 0; j < 2; j++)
#pragma unroll
        for (int ks = 0; ks < 2; ks++)
            b3[j][ks] = *(const f16x8*)&W3T[((ntbase + j) * 16 + r) * 72 + ks * 32 + q * 8];

    // ---- per-window counting sort in LDS (identical to R14 — determinism anchor) ----
    if (tid < 64) cnt[tid] = 0;
    __syncthreads();
    for (int i = tid; i < len; i += 512) atomicAdd(&cnt[colw[base + i] & 63], 1);
    __syncthreads();
    if (tid < 64) {
        int v = cnt[tid];
        int incl = waveInclScan(v, tid);
        start[tid] = incl - v;
        cur[tid] = incl - v;
    }
    __syncthreads();
    for (int i = tid; i < len; i += 512) {
        int pk = colw[base + i];
        int pos = atomicAdd(&cur[pk & 63], 1);
        sorted[pos] = pk >> 6;
    }
    __syncthreads();

    // ---- paired gather + LN + relu: 4 nodes per group as 2 interleaved pairs ----
#pragma unroll
    for (int pr = 0; pr < 2; pr++) {
        int tlA = grp + 32 * pr;
        int tlB = tlA + 16;
        int nA = nb + tlA, nB = nb + tlB;
        int lenA = (nA < N) ? cnt[tlA] : 0;
        int lenB = (nB < N) ? cnt[tlB] : 0;
        int s0A = start[tlA], s0B = start[tlB];
        int mx = lenA > lenB ? lenA : lenB;
        float2 aA0 = make_float2(0.f, 0.f), aA1 = aA0, aA2 = aA0, aA3 = aA0;
        float2 aB0 = aA0, aB1 = aA0, aB2 = aA0, aB3 = aA0;
        for (int i = 0; i < mx; i += 4) {
            GATH4(p1v, 32u, cc, s0A, lenA, i, aA0, aA1, aA2, aA3)
            GATH4(p1v, 32u, cc, s0B, lenB, i, aB0, aB1, aB2, aB3)
        }
        F2ADD(aA0, aA2) F2ADD(aA1, aA3) F2ADD(aA0, aA1)
        F2ADD(aB0, aB2) F2ADD(aB1, aB3) F2ADD(aB0, aB1)
#pragma unroll
        for (int sel = 0; sel < 2; sel++) {
            int tl = sel ? tlB : tlA;
            int n = sel ? nB : nA;
            int cntv = sel ? lenB : lenA;
            float2 ag = sel ? aB0 : aA0;
            if (n < N) {
                float inv = 1.f / (float)(cntv > 1 ? cntv : 1);
                float2 rr = __half22float2(r1v[(unsigned)n * 32u + cc]);
                float vx = ag.x * inv + rr.x;
                float vy = ag.y * inv + rr.y;
                float s = vx + vy;
#pragma unroll
                for (int o = 1; o < 32; o <<= 1) s += __shfl_xor(s, o, 32);
                float m = s * (1.f / 64.f);
                float dx = vx - m, dy = vy - m;
                float qv = dx * dx + dy * dy;
#pragma unroll
                for (int o = 1; o < 32; o <<= 1) qv += __shfl_xor(qv, o, 32);
                float rs = rsqrtf(qv * (1.f / 64.f) + EPS);
                float y0 = dx * rs * g1[2 * cc] + be1[2 * cc];
                float y1 = dy * rs * g1[2 * cc + 1] + be1[2 * cc + 1];
                ys[tl][2 * cc]     = (f16)(y0 > 0.f ? y0 : 0.f);
                ys[tl][2 * cc + 1] = (f16)(y1 > 0.f ? y1 : 0.f);
            } else {
                ys[tl][2 * cc] = (f16)0.f;
                ys[tl][2 * cc + 1] = (f16)0.f;
            }
        }
    }
    __syncthreads();

    // ---- proj2 via MFMA: [64 x 64] @ [64 x 64], 16 tile-jobs, 2 per wave ----
#pragma unroll
    for (int j = 0; j < 2; j++) {
        int nt = ntbase + j;
        f32x4 acc = {};
#pragma unroll
        for (int ks = 0; ks < 2; ks++) {
            f16x8 a = *(const f16x8*)&ys[mt * 16 + r][ks * 32 + q * 8];
            acc = __builtin_amdgcn_mfma_f32_16x16x32_f16(a, b3[j][ks], acc, 0, 0, 0);
        }
        int c2 = nt * 16 + r;
        float bb = (c2 >= 32) ? bl2[c2 - 32] : 0.f;
#pragma unroll
        for (int v = 0; v < 4; v++) {
            int n = nb + mt * 16 + q * 4 + v;
            if (n < N) {
                float val = acc[v];
                if (c2 < 32) p2h[(size_t)n * 32 + c2] = (f16)val;
                else         r2h[(size_t)n * 32 + (c2 - 32)] = (f16)(val + bb);
            }
        }
    }
}

// ---------------- agg2 (per-window, one block): LDS sort -> paired gather+LN -> MFMA MLP ----------------
__global__ __launch_bounds__(512) void k_agg2_out(const __half2* __restrict__ p2v,
                                                  const __half2* __restrict__ r2v,
                                                  const int* __restrict__ wcur,
                                                  const int* __restrict__ colw,
                                                  const float* __restrict__ g2,
                                                  const float* __restrict__ be2,
                                                  const f16* __restrict__ Wo1T,
                                                  const float* __restrict__ bo1,
                                                  const float* __restrict__ Wo2,
                                                  const float* __restrict__ bo2,
                                                  float* __restrict__ out, int N) {
    __shared__ int cnt[64], start[64], cur[64];
    __shared__ int sorted[CAP];
    __shared__ __align__(16) f16 ys[64][40];
    int tid = threadIdx.x;
    int wb = blockIdx.x;
    int base = wb * CAP;
    int nb = wb << 6;
    int len = wcur[wb] - base;
    if (len > CAP) len = CAP;

    unsigned l = tid & 15;
    int grp = tid >> 4;       // 32 groups of 16 lanes
    int lane = tid & 63;
    int wv = tid >> 6;        // 8 waves; waves 0..3 do the MFMA
    int r = lane & 15;
    int q = lane >> 4;

    f16x8 bo = *(const f16x8*)&Wo1T[r * 40 + q * 8];
    float b1v = bo1[r];
    float w2v = Wo2[r];

    if (tid < 64) cnt[tid] = 0;
    __syncthreads();
    for (int i = tid; i < len; i += 512) atomicAdd(&cnt[colw[base + i] & 63], 1);
    __syncthreads();
    if (tid < 64) {
        int v = cnt[tid];
        int incl = waveInclScan(v, tid);
        start[tid] = incl - v;
        cur[tid] = incl - v;
    }
    __syncthreads();
    for (int i = tid; i < len; i += 512) {
        int pk = colw[base + i];
        int pos = atomicAdd(&cur[pk & 63], 1);
        sorted[pos] = pk >> 6;
    }
    __syncthreads();

    // paired gather + LN + relu: nodes (grp, grp+32) interleaved
    {
        int tlA = grp;
        int tlB = grp + 32;
        int nA = nb + tlA, nB = nb + tlB;
        int lenA = (nA < N) ? cnt[tlA] : 0;
        int lenB = (nB < N) ? cnt[tlB] : 0;
        int s0A = start[tlA], s0B = start[tlB];
        int mx = lenA > lenB ? lenA : lenB;
        float2 aA0 = make_float2(0.f, 0.f), aA1 = aA0, aA2 = aA0, aA3 = aA0;
        float2 aB0 = aA0, aB1 = aA0, aB2 = aA0, aB3 = aA0;
        for (int i = 0; i < mx; i += 4) {
            GATH4(p2v, 16u, l, s0A, lenA, i, aA0, aA1, aA2, aA3)
            GATH4(p2v, 16u, l, s0B, lenB, i, aB0, aB1, aB2, aB3)
        }
        F2ADD(aA0, aA2) F2ADD(aA1, aA3) F2ADD(aA0, aA1)
        F2ADD(aB0, aB2) F2ADD(aB1, aB3) F2ADD(aB0, aB1)
#pragma unroll
        for (int sel = 0; sel < 2; sel++) {
            int tl = sel ? tlB : tlA;
            int n = sel ? nB : nA;
            int cntv = sel ? lenB : lenA;
            float2 ag = sel ? aB0 : aA0;
            if (n < N) {
                float inv = 1.f / (float)(cntv > 1 ? cntv : 1);
                float2 rr = __half22float2(r2v[(unsigned)n * 16u + l]);
                float vx = ag.x * inv + rr.x;
                float vy = ag.y * inv + rr.y;
                float s = vx + vy;
#pragma unroll
                for (int o = 1; o < 16; o <<= 1) s += __shfl_xor(s, o, 16);
                float m = s * (1.f / 32.f);
                float dx = vx - m, dy = vy - m;
                float qv = dx * dx + dy * dy;
#pragma unroll
                for (int o = 1; o < 16; o <<= 1) qv += __shfl_xor(qv, o, 16);
                float rs = rsqrtf(qv * (1.f / 32.f) + EPS);
                float y0 = dx * rs * g2[2 * l] + be2[2 * l];
                float y1 = dy * rs * g2[2 * l + 1] + be2[2 * l + 1];
                ys[tl][2 * l]     = (f16)(y0 > 0.f ? y0 : 0.f);
                ys[tl][2 * l + 1] = (f16)(y1 > 0.f ? y1 : 0.f);
            } else {
                ys[tl][2 * l] = (f16)0.f;
                ys[tl][2 * l + 1] = (f16)0.f;
            }
        }
    }
    __syncthreads();

    // MLP: hidden = relu(y@Wo1+bo1) via MFMA, out = hidden@Wo2 + bo2 via reduce
    if (wv < 4) {
        f16x8 a = *(const f16x8*)&ys[wv * 16 + r][q * 8];
        f32x4 acc = {};
        acc = __builtin_amdgcn_mfma_f32_16x16x32_f16(a, bo, acc, 0, 0, 0);
#pragma unroll
        for (int v = 0; v < 4; v++) {
            float h = acc[v] + b1v;
            h = h > 0.f ? h : 0.f;
            float contrib = h * w2v;
#pragma unroll
            for (int o = 1; o < 16; o <<= 1) contrib += __shfl_xor(contrib, o, 16);
            int n = nb + wv * 16 + q * 4 + v;
            if (r == 0 && n < N) out[n] = contrib + bo2[0];
        }
    }
}

extern "C" void kernel_launch(void* const* d_in, const int* in_sizes, int n_in,
                              void* d_out, int out_size, void* d_ws, size_t ws_size,
                              hipStream_t stream) {
    const float* x    = (const float*)d_in[0];
    const int*   ei   = (const int*)d_in[1];
    const float* W_in = (const float*)d_in[2];
    const float* b_in = (const float*)d_in[3];
    const float* Wl1  = (const float*)d_in[4];
    const float* bl1  = (const float*)d_in[5];
    const float* Wr1  = (const float*)d_in[6];
    const float* g1   = (const float*)d_in[7];
    const float* be1  = (const float*)d_in[8];
    const float* Wl2  = (const float*)d_in[9];
    const float* bl2  = (const float*)d_in[10];
    const float* Wr2  = (const float*)d_in[11];
    const float* g2   = (const float*)d_in[12];
    const float* be2  = (const float*)d_in[13];
    const float* Wo1  = (const float*)d_in[14];
    const float* bo1  = (const float*)d_in[15];
    const float* Wo2  = (const float*)d_in[16];
    const float* bo2  = (const float*)d_in[17];
    float* out = (float*)d_out;

    const int N = NN, E = NE;
    const int* src = ei;
    const int* tgt = ei + E;

    // workspace layout
    char* w = (char*)d_ws;
    int* wcur = (int*)w;  w += (size_t)NW * 4;
    w = (char*)(((uintptr_t)w + 15) & ~(uintptr_t)15);
    int* colw = (int*)w;  w += (size_t)NW * CAP * 4;     // 8.0 MB, CAP-strided
    f16* p1h  = (f16*)w;  w += (size_t)N * 64 * 2;
    f16* r1h  = (f16*)w;  w += (size_t)N * 64 * 2;
    f16* p2h  = (f16*)w;  w += (size_t)N * 32 * 2;
    f16* r2h  = (f16*)w;  w += (size_t)N * 32 * 2;
    f16* WinT = (f16*)w;  w += (size_t)128 * 104 * 2;
    f16* W2T  = (f16*)w;  w += (size_t)128 * 136 * 2;
    f16* W3T  = (f16*)w;  w += (size_t)64 * 72 * 2;
    f16* Wo1T = (f16*)w;  w += (size_t)16 * 40 * 2;

    // ---- 4-dispatch pipeline ----
    k_prep_init<<<PREPB, 256, 0, stream>>>(W_in, Wl1, Wr1, Wl2, Wr2, Wo1,
                                           WinT, W2T, W3T, Wo1T, wcur);
    k_wfill_inproj<<<WFB + INPB, 256, 0, stream>>>(src, tgt, wcur, colw,
                                                   x, WinT, b_in, W2T, bl1, p1h, r1h, N);
    k_agg1_proj2<<<NW, 512, 0, stream>>>((const __half2*)p1h, (const __half2*)r1h,
                                         wcur, colw, g1, be1, W3T, bl2, p2h, r2h, N);
    k_agg2_out<<<NW, 512, 0, stream>>>((const __half2*)p2h, (const __half2*)r2h,
                                       wcur, colw, g2, be2, Wo1T, bo1, Wo2, bo2, out, N);
}

// Round 17
// 76.154 us; speedup vs baseline: 1.0968x; 1.0968x over previous
//
#include <hip/hip_runtime.h>
#include <hip/hip_bf16.h>
#include <hip/hip_fp16.h>

#define NN 50000
#define NE 800000
#define EPS 1e-5f
#define NW 782            // ceil(NN/64) windows of 64 nodes
#define CAP 2560          // fixed per-window colw slots (max window load ~1150)
#define WFB 200           // wfill blocks
#define CHUNK (NE / WFB)  // 4000 edges per wfill block
#define PREPB 64          // prep blocks
#define INPB ((NN + 31) / 32)

typedef _Float16 f16;
typedef _Float16 f16x8 __attribute__((ext_vector_type(8)));
typedef float f32x4 __attribute__((ext_vector_type(4)));

#define F2ADD(a, b) { (a).x += (b).x; (a).y += (b).y; }

__device__ __forceinline__ int waveInclScan(int v, int lane) {
#pragma unroll
    for (int o = 1; o < 64; o <<= 1) {
        int t = __shfl_up(v, o, 64);
        if (lane >= o) v += t;
    }
    return v;
}

// ---------------- prep: weight transposes + wcur init ----------------
__global__ __launch_bounds__(256) void k_prep_init(const float* __restrict__ Win,
                                                   const float* __restrict__ Wl,
                                                   const float* __restrict__ Wr,
                                                   const float* __restrict__ Wl2,
                                                   const float* __restrict__ Wr2,
                                                   const float* __restrict__ Wo1,
                                                   f16* __restrict__ WinT,
                                                   f16* __restrict__ W2T,
                                                   f16* __restrict__ W3T,
                                                   f16* __restrict__ Wo1T,
                                                   int* __restrict__ wcur) {
    int i0 = blockIdx.x * 256 + threadIdx.x;
    for (int i = i0; i < 128 * 104; i += PREPB * 256) {
        int c = i / 104, k = i - c * 104;
        float v = (k < 84) ? Win[k * 128 + c] : 0.f;
        WinT[c * 104 + k] = (f16)v;
    }
    for (int i = i0; i < 128 * 136; i += PREPB * 256) {
        int c = i / 136, k = i - c * 136;
        float v = 0.f;
        if (k < 128) v = (c < 64) ? Wl[k * 64 + c] : Wr[k * 64 + (c - 64)];
        W2T[c * 136 + k] = (f16)v;
    }
    for (int i = i0; i < 64 * 72; i += PREPB * 256) {
        int c = i / 72, k = i - c * 72;
        float v = 0.f;
        if (k < 64) v = (c < 32) ? Wl2[k * 32 + c] : Wr2[k * 32 + (c - 32)];
        W3T[c * 72 + k] = (f16)v;
    }
    for (int i = i0; i < 16 * 40; i += PREPB * 256) {
        int c = i / 40, k = i - c * 40;
        float v = (k < 32) ? Wo1[k * 16 + c] : 0.f;
        Wo1T[c * 40 + k] = (f16)v;
    }
    for (int i = i0; i < NW; i += PREPB * 256) wcur[i] = i * CAP;
}

// ---------------- fused: wfill (blocks <WFB) | MFMA in_proj1 (rest) ----------------
__global__ __launch_bounds__(256) void k_wfill_inproj(const int* __restrict__ src,
                                                      const int* __restrict__ tgt,
                                                      int* __restrict__ wcur,
                                                      int* __restrict__ colw,
                                                      const float* __restrict__ x,
                                                      const f16* __restrict__ WinT,
                                                      const float* __restrict__ bin,
                                                      const f16* __restrict__ W2T,
                                                      const float* __restrict__ bl,
                                                      f16* __restrict__ p1h,
                                                      f16* __restrict__ r1h, int N) {
    __shared__ int lh[NW];
    __shared__ int sb[NW];
    __shared__ __align__(16) f16 xs[32 * 104];
    __shared__ __align__(16) f16 hs[32 * 136];
    int tid = threadIdx.x;

    if (blockIdx.x < WFB) {
        // span-reserved window partition into CAP-strided colw
        int i4lo = (blockIdx.x * CHUNK) >> 2;
        int i4hi = i4lo + (CHUNK >> 2);
        for (int i = tid; i < NW; i += 256) lh[i] = 0;
        __syncthreads();
        for (int i4 = i4lo + tid; i4 < i4hi; i4 += 256) {
            int4 t = ((const int4*)tgt)[i4];
            atomicAdd(&lh[t.x >> 6], 1);
            atomicAdd(&lh[t.y >> 6], 1);
            atomicAdd(&lh[t.z >> 6], 1);
            atomicAdd(&lh[t.w >> 6], 1);
        }
        __syncthreads();
        for (int i = tid; i < NW; i += 256) {
            int c = lh[i];
            sb[i] = c ? atomicAdd(&wcur[i], c) : 0;
            lh[i] = 0;
        }
        __syncthreads();
        for (int i4 = i4lo + tid; i4 < i4hi; i4 += 256) {
            int4 t = ((const int4*)tgt)[i4];
            int4 s = ((const int4*)src)[i4];
            int w0 = t.x >> 6, r0 = atomicAdd(&lh[w0], 1);
            colw[sb[w0] + r0] = (s.x << 6) | (t.x & 63);
            int w1 = t.y >> 6, r1 = atomicAdd(&lh[w1], 1);
            colw[sb[w1] + r1] = (s.y << 6) | (t.y & 63);
            int w2 = t.z >> 6, r2 = atomicAdd(&lh[w2], 1);
            colw[sb[w2] + r2] = (s.z << 6) | (t.z & 63);
            int w3 = t.w >> 6, r3 = atomicAdd(&lh[w3], 1);
            colw[sb[w3] + r3] = (s.w << 6) | (t.w & 63);
        }
        return;
    }

    // ---- in_proj1: x -> h1 (LDS) -> p1, r1 via MFMA ----
    int node0 = (blockIdx.x - WFB) * 32;
    int lane = tid & 63;
    int wv = tid >> 6;
    int r = lane & 15;
    int q = lane >> 4;

    f16x8 b1[2][3];
#pragma unroll
    for (int nt = 0; nt < 2; nt++) {
        int c = (2 * wv + nt) * 16 + r;
#pragma unroll
        for (int ks = 0; ks < 3; ks++)
            b1[nt][ks] = *(const f16x8*)&WinT[c * 104 + ks * 32 + q * 8];
    }
    // float4-vectorized x staging
    for (int i = tid; i < 672; i += 256) {
        int nd = i / 21, k4 = i - nd * 21;
        int g = node0 + nd;
        float4 v = make_float4(0.f, 0.f, 0.f, 0.f);
        if (g < N) v = ((const float4*)x)[(size_t)g * 21 + k4];
        f16* dst = &xs[nd * 104 + k4 * 4];
        dst[0] = (f16)v.x; dst[1] = (f16)v.y; dst[2] = (f16)v.z; dst[3] = (f16)v.w;
    }
    for (int i = tid; i < 32 * 12; i += 256) {
        int nd = i / 12, k = 84 + (i - nd * 12);
        xs[nd * 104 + k] = (f16)0.f;
    }
    __syncthreads();

    f32x4 acc[2][2] = {};
#pragma unroll
    for (int ks = 0; ks < 3; ks++) {
        int k0 = ks * 32;
        f16x8 a[2];
#pragma unroll
        for (int mt = 0; mt < 2; mt++)
            a[mt] = *(const f16x8*)&xs[(mt * 16 + r) * 104 + k0 + q * 8];
#pragma unroll
        for (int mt = 0; mt < 2; mt++)
#pragma unroll
            for (int nt = 0; nt < 2; nt++)
                acc[mt][nt] = __builtin_amdgcn_mfma_f32_16x16x32_f16(a[mt], b1[nt][ks], acc[mt][nt], 0, 0, 0);
    }

    f16x8 b2[2][4];
#pragma unroll
    for (int nt = 0; nt < 2; nt++) {
        int c = (2 * wv + nt) * 16 + r;
#pragma unroll
        for (int ks = 0; ks < 4; ks++)
            b2[nt][ks] = *(const f16x8*)&W2T[c * 136 + ks * 32 + q * 8];
    }

#pragma unroll
    for (int nt = 0; nt < 2; nt++) {
        int c = (2 * wv + nt) * 16 + r;
        float bb = bin[c];
#pragma unroll
        for (int mt = 0; mt < 2; mt++)
#pragma unroll
            for (int v = 0; v < 4; v++) {
                int row = mt * 16 + q * 4 + v;
                float val = acc[mt][nt][v] + bb;
                hs[row * 136 + c] = (f16)(val > 0.f ? val : 0.f);
            }
    }
    __syncthreads();

    f32x4 acc2[2][2] = {};
#pragma unroll
    for (int ks = 0; ks < 4; ks++) {
        int k0 = ks * 32;
        f16x8 a[2];
#pragma unroll
        for (int mt = 0; mt < 2; mt++)
            a[mt] = *(const f16x8*)&hs[(mt * 16 + r) * 136 + k0 + q * 8];
#pragma unroll
        for (int mt = 0; mt < 2; mt++)
#pragma unroll
            for (int nt = 0; nt < 2; nt++)
                acc2[mt][nt] = __builtin_amdgcn_mfma_f32_16x16x32_f16(a[mt], b2[nt][ks], acc2[mt][nt], 0, 0, 0);
    }

    // epilogue 2: repack into hs (dead after GEMM2), then coalesced f16x8 stores
    __syncthreads();
#pragma unroll
    for (int nt = 0; nt < 2; nt++) {
        int c = (2 * wv + nt) * 16 + r;
        float bb = (c >= 64) ? bl[c - 64] : 0.f;
#pragma unroll
        for (int mt = 0; mt < 2; mt++)
#pragma unroll
            for (int v = 0; v < 4; v++) {
                int row = mt * 16 + q * 4 + v;
                hs[row * 136 + c] = (f16)(acc2[mt][nt][v] + bb);
            }
    }
    __syncthreads();
    {
        int row = tid >> 3, c8 = tid & 7;   // 32 rows x 8 chunks
        int n = node0 + row;
        if (n < N) {
            f16x8 vp = *(const f16x8*)&hs[row * 136 + c8 * 8];
            *(f16x8*)&p1h[(size_t)n * 64 + c8 * 8] = vp;
            f16x8 vr = *(const f16x8*)&hs[row * 136 + 64 + c8 * 8];
            *(f16x8*)&r1h[(size_t)n * 64 + c8 * 8] = vr;
        }
    }
}

// masked gather step: 4 loads per node (identical per-node math to R16)
#define GATH4(pv, STRIDE, LANE, s0, len, i, A0, A1, A2, A3)                          \
    {                                                                                \
        int i0_ = i, i1_ = i + 1, i2_ = i + 2, i3_ = i + 3;                          \
        unsigned x0_ = (i0_ < len) ? (unsigned)sorted[s0 + i0_] : 0u;                \
        unsigned x1_ = (i1_ < len) ? (unsigned)sorted[s0 + i1_] : 0u;                \
        unsigned x2_ = (i2_ < len) ? (unsigned)sorted[s0 + i2_] : 0u;                \
        unsigned x3_ = (i3_ < len) ? (unsigned)sorted[s0 + i3_] : 0u;                \
        float m0_ = (i0_ < len) ? 1.f : 0.f;                                         \
        float m1_ = (i1_ < len) ? 1.f : 0.f;                                         \
        float m2_ = (i2_ < len) ? 1.f : 0.f;                                         \
        float m3_ = (i3_ < len) ? 1.f : 0.f;                                         \
        float2 v0_ = __half22float2(pv[x0_ * STRIDE + LANE]);                        \
        float2 v1_ = __half22float2(pv[x1_ * STRIDE + LANE]);                        \
        float2 v2_ = __half22float2(pv[x2_ * STRIDE + LANE]);                        \
        float2 v3_ = __half22float2(pv[x3_ * STRIDE + LANE]);                        \
        A0.x += m0_ * v0_.x; A0.y += m0_ * v0_.y;                                    \
        A1.x += m1_ * v1_.x; A1.y += m1_ * v1_.y;                                    \
        A2.x += m2_ * v2_.x; A2.y += m2_ * v2_.y;                                    \
        A3.x += m3_ * v3_.x; A3.y += m3_ * v3_.y;                                    \
    }

// ---------------- agg1 (per-window, ONE 1024-thr block): LDS sort -> gather+LN -> MFMA proj2 ----------------
__global__ __launch_bounds__(1024) void k_agg1_proj2(const __half2* __restrict__ p1v,
                                                     const __half2* __restrict__ r1v,
                                                     const int* __restrict__ wcur,
                                                     const int* __restrict__ colw,
                                                     const float* __restrict__ g1,
                                                     const float* __restrict__ be1,
                                                     const f16* __restrict__ W3T,
                                                     const float* __restrict__ bl2,
                                                     f16* __restrict__ p2h,
                                                     f16* __restrict__ r2h, int N) {
    __shared__ int cnt[64], start[64], cur[64];
    __shared__ int sorted[CAP];
    __shared__ __align__(16) f16 ys[64][72];
    int tid = threadIdx.x;
    int wb = blockIdx.x;
    int base = wb * CAP;
    int nb = wb << 6;
    int len = wcur[wb] - base;
    if (len > CAP) len = CAP;

    unsigned cc = tid & 31;
    int grp = tid >> 5;       // 32 groups of 32 lanes
    int lane = tid & 63;
    int wv = tid >> 6;        // 16 waves
    int r = lane & 15;
    int q = lane >> 4;

    // proj2 B-fragments: each of 16 waves owns one 16x16 output tile (mt, nt)
    int mt = wv & 3;
    int nt = wv >> 2;
    f16x8 b3[2];
#pragma unroll
    for (int ks = 0; ks < 2; ks++)
        b3[ks] = *(const f16x8*)&W3T[(nt * 16 + r) * 72 + ks * 32 + q * 8];

    // ---- per-window counting sort in LDS ----
    if (tid < 64) cnt[tid] = 0;
    __syncthreads();
    for (int i = tid; i < len; i += 1024) atomicAdd(&cnt[colw[base + i] & 63], 1);
    __syncthreads();
    if (tid < 64) {
        int v = cnt[tid];
        int incl = waveInclScan(v, tid);
        start[tid] = incl - v;
        cur[tid] = incl - v;
    }
    __syncthreads();
    for (int i = tid; i < len; i += 1024) {
        int pk = colw[base + i];
        int pos = atomicAdd(&cur[pk & 63], 1);
        sorted[pos] = pk >> 6;
    }
    __syncthreads();

    // ---- paired gather + LN + relu: 2 nodes per 32-lane group ----
    {
        int tlA = grp;
        int tlB = grp + 32;
        int nA = nb + tlA, nB = nb + tlB;
        int lenA = (nA < N) ? cnt[tlA] : 0;
        int lenB = (nB < N) ? cnt[tlB] : 0;
        int s0A = start[tlA], s0B = start[tlB];
        int mx = lenA > lenB ? lenA : lenB;
        float2 aA0 = make_float2(0.f, 0.f), aA1 = aA0, aA2 = aA0, aA3 = aA0;
        float2 aB0 = aA0, aB1 = aA0, aB2 = aA0, aB3 = aA0;
        for (int i = 0; i < mx; i += 4) {
            GATH4(p1v, 32u, cc, s0A, lenA, i, aA0, aA1, aA2, aA3)
            GATH4(p1v, 32u, cc, s0B, lenB, i, aB0, aB1, aB2, aB3)
        }
        F2ADD(aA0, aA2) F2ADD(aA1, aA3) F2ADD(aA0, aA1)
        F2ADD(aB0, aB2) F2ADD(aB1, aB3) F2ADD(aB0, aB1)
#pragma unroll
        for (int sel = 0; sel < 2; sel++) {
            int tl = sel ? tlB : tlA;
            int n = sel ? nB : nA;
            int cntv = sel ? lenB : lenA;
            float2 ag = sel ? aB0 : aA0;
            if (n < N) {
                float inv = 1.f / (float)(cntv > 1 ? cntv : 1);
                float2 rr = __half22float2(r1v[(unsigned)n * 32u + cc]);
                float vx = ag.x * inv + rr.x;
                float vy = ag.y * inv + rr.y;
                float s = vx + vy;
#pragma unroll
                for (int o = 1; o < 32; o <<= 1) s += __shfl_xor(s, o, 32);
                float m = s * (1.f / 64.f);
                float dx = vx - m, dy = vy - m;
                float qv = dx * dx + dy * dy;
#pragma unroll
                for (int o = 1; o < 32; o <<= 1) qv += __shfl_xor(qv, o, 32);
                float rs = rsqrtf(qv * (1.f / 64.f) + EPS);
                float y0 = dx * rs * g1[2 * cc] + be1[2 * cc];
                float y1 = dy * rs * g1[2 * cc + 1] + be1[2 * cc + 1];
                ys[tl][2 * cc]     = (f16)(y0 > 0.f ? y0 : 0.f);
                ys[tl][2 * cc + 1] = (f16)(y1 > 0.f ? y1 : 0.f);
            } else {
                ys[tl][2 * cc] = (f16)0.f;
                ys[tl][2 * cc + 1] = (f16)0.f;
            }
        }
    }
    __syncthreads();

    // ---- proj2 via MFMA: [64 x 64] @ [64 x 64], one 16x16 tile per wave ----
    {
        f32x4 acc = {};
#pragma unroll
        for (int ks = 0; ks < 2; ks++) {
            f16x8 a = *(const f16x8*)&ys[mt * 16 + r][ks * 32 + q * 8];
            acc = __builtin_amdgcn_mfma_f32_16x16x32_f16(a, b3[ks], acc, 0, 0, 0);
        }
        int c2 = nt * 16 + r;
        float bb = (c2 >= 32) ? bl2[c2 - 32] : 0.f;
#pragma unroll
        for (int v = 0; v < 4; v++) {
            int n = nb + mt * 16 + q * 4 + v;
            if (n < N) {
                float val = acc[v];
                if (c2 < 32) p2h[(size_t)n * 32 + c2] = (f16)val;
                else         r2h[(size_t)n * 32 + (c2 - 32)] = (f16)(val + bb);
            }
        }
    }
}

// ---------------- agg2 (per-window, ONE 1024-thr block): LDS sort -> gather+LN -> MFMA MLP ----------------
__global__ __launch_bounds__(1024) void k_agg2_out(const __half2* __restrict__ p2v,
                                                   const __half2* __restrict__ r2v,
                                                   const int* __restrict__ wcur,
                                                   const int* __restrict__ colw,
                                                   const float* __restrict__ g2,
                                                   const float* __restrict__ be2,
                                                   const f16* __restrict__ Wo1T,
                                                   const float* __restrict__ bo1,
                                                   const float* __restrict__ Wo2,
                                                   const float* __restrict__ bo2,
                                                   float* __restrict__ out, int N) {
    __shared__ int cnt[64], start[64], cur[64];
    __shared__ int sorted[CAP];
    __shared__ __align__(16) f16 ys[64][40];
    int tid = threadIdx.x;
    int wb = blockIdx.x;
    int base = wb * CAP;
    int nb = wb << 6;
    int len = wcur[wb] - base;
    if (len > CAP) len = CAP;

    unsigned l = tid & 15;
    int grp = tid >> 4;       // 64 groups of 16 lanes, one node each
    int lane = tid & 63;
    int wv = tid >> 6;        // 16 waves; waves 0..3 do the MFMA
    int r = lane & 15;
    int q = lane >> 4;

    f16x8 bo = *(const f16x8*)&Wo1T[r * 40 + q * 8];
    float b1v = bo1[r];
    float w2v = Wo2[r];

    if (tid < 64) cnt[tid] = 0;
    __syncthreads();
    for (int i = tid; i < len; i += 1024) atomicAdd(&cnt[colw[base + i] & 63], 1);
    __syncthreads();
    if (tid < 64) {
        int v = cnt[tid];
        int incl = waveInclScan(v, tid);
        start[tid] = incl - v;
        cur[tid] = incl - v;
    }
    __syncthreads();
    for (int i = tid; i < len; i += 1024) {
        int pk = colw[base + i];
        int pos = atomicAdd(&cur[pk & 63], 1);
        sorted[pos] = pk >> 6;
    }
    __syncthreads();

    // gather + LN + relu: one node per 16-lane group (masked 4-acc, same per-node math)
    {
        int tl = grp;
        int n = nb + tl;
        int lenA = (n < N) ? cnt[tl] : 0;
        int s0A = start[tl];
        float2 a0 = make_float2(0.f, 0.f), a1 = a0, a2 = a0, a3 = a0;
        for (int i = 0; i < lenA; i += 4) {
            GATH4(p2v, 16u, l, s0A, lenA, i, a0, a1, a2, a3)
        }
        F2ADD(a0, a2) F2ADD(a1, a3) F2ADD(a0, a1)
        if (n < N) {
            float inv = 1.f / (float)(lenA > 1 ? lenA : 1);
            float2 rr = __half22float2(r2v[(unsigned)n * 16u + l]);
            float vx = a0.x * inv + rr.x;
            float vy = a0.y * inv + rr.y;
            float s = vx + vy;
#pragma unroll
            for (int o = 1; o < 16; o <<= 1) s += __shfl_xor(s, o, 16);
            float m = s * (1.f / 32.f);
            float dx = vx - m, dy = vy - m;
            float qv = dx * dx + dy * dy;
#pragma unroll
            for (int o = 1; o < 16; o <<= 1) qv += __shfl_xor(qv, o, 16);
            float rs = rsqrtf(qv * (1.f / 32.f) + EPS);
            float y0 = dx * rs * g2[2 * l] + be2[2 * l];
            float y1 = dy * rs * g2[2 * l + 1] + be2[2 * l + 1];
            ys[tl][2 * l]     = (f16)(y0 > 0.f ? y0 : 0.f);
            ys[tl][2 * l + 1] = (f16)(y1 > 0.f ? y1 : 0.f);
        } else {
            ys[tl][2 * l] = (f16)0.f;
            ys[tl][2 * l + 1] = (f16)0.f;
        }
    }
    __syncthreads();

    // MLP: hidden = relu(y@Wo1+bo1) via MFMA, out = hidden@Wo2 + bo2 via reduce
    if (wv < 4) {
        f16x8 a = *(const f16x8*)&ys[wv * 16 + r][q * 8];
        f32x4 acc = {};
        acc = __builtin_amdgcn_mfma_f32_16x16x32_f16(a, bo, acc, 0, 0, 0);
#pragma unroll
        for (int v = 0; v < 4; v++) {
            float h = acc[v] + b1v;
            h = h > 0.f ? h : 0.f;
            float contrib = h * w2v;
#pragma unroll
            for (int o = 1; o < 16; o <<= 1) contrib += __shfl_xor(contrib, o, 16);
            int n = nb + wv * 16 + q * 4 + v;
            if (r == 0 && n < N) out[n] = contrib + bo2[0];
        }
    }
}

extern "C" void kernel_launch(void* const* d_in, const int* in_sizes, int n_in,
                              void* d_out, int out_size, void* d_ws, size_t ws_size,
                              hipStream_t stream) {
    const float* x    = (const float*)d_in[0];
    const int*   ei   = (const int*)d_in[1];
    const float* W_in = (const float*)d_in[2];
    const float* b_in = (const float*)d_in[3];
    const float* Wl1  = (const float*)d_in[4];
    const float* bl1  = (const float*)d_in[5];
    const float* Wr1  = (const float*)d_in[6];
    const float* g1   = (const float*)d_in[7];
    const float* be1  = (const float*)d_in[8];
    const float* Wl2  = (const float*)d_in[9];
    const float* bl2  = (const float*)d_in[10];
    const float* Wr2  = (const float*)d_in[11];
    const float* g2   = (const float*)d_in[12];
    const float* be2  = (const float*)d_in[13];
    const float* Wo1  = (const float*)d_in[14];
    const float* bo1  = (const float*)d_in[15];
    const float* Wo2  = (const float*)d_in[16];
    const float* bo2  = (const float*)d_in[17];
    float* out = (float*)d_out;

    const int N = NN, E = NE;
    const int* src = ei;
    const int* tgt = ei + E;

    // workspace layout
    char* w = (char*)d_ws;
    int* wcur = (int*)w;  w += (size_t)NW * 4;
    w = (char*)(((uintptr_t)w + 15) & ~(uintptr_t)15);
    int* colw = (int*)w;  w += (size_t)NW * CAP * 4;     // 8.0 MB, CAP-strided
    f16* p1h  = (f16*)w;  w += (size_t)N * 64 * 2;
    f16* r1h  = (f16*)w;  w += (size_t)N * 64 * 2;
    f16* p2h  = (f16*)w;  w += (size_t)N * 32 * 2;
    f16* r2h  = (f16*)w;  w += (size_t)N * 32 * 2;
    f16* WinT = (f16*)w;  w += (size_t)128 * 104 * 2;
    f16* W2T  = (f16*)w;  w += (size_t)128 * 136 * 2;
    f16* W3T  = (f16*)w;  w += (size_t)64 * 72 * 2;
    f16* Wo1T = (f16*)w;  w += (size_t)16 * 40 * 2;

    // ---- 4-dispatch pipeline ----
    k_prep_init<<<PREPB, 256, 0, stream>>>(W_in, Wl1, Wr1, Wl2, Wr2, Wo1,
                                           WinT, W2T, W3T, Wo1T, wcur);
    k_wfill_inproj<<<WFB + INPB, 256, 0, stream>>>(src, tgt, wcur, colw,
                                                   x, WinT, b_in, W2T, bl1, p1h, r1h, N);
    k_agg1_proj2<<<NW, 1024, 0, stream>>>((const __half2*)p1h, (const __half2*)r1h,
                                          wcur, colw, g1, be1, W3T, bl2, p2h, r2h, N);
    k_agg2_out<<<NW, 1024, 0, stream>>>((const __half2*)p2h, (const __half2*)r2h,
                                        wcur, colw, g2, be2, Wo1T, bo1, Wo2, bo2, out, N);
}

// Round 18
// 75.713 us; speedup vs baseline: 1.1032x; 1.0058x over previous
//
#include <hip/hip_runtime.h>
#include <hip/hip_bf16.h>
#include <hip/hip_fp16.h>

#define NN 50000
#define NE 800000
#define EPS 1e-5f
#define NW 782            // ceil(NN/64) windows of 64 nodes
#define CAP 2560          // fixed per-window colw slots (max window load ~1150)
#define WFB 200           // wfill blocks
#define CHUNK (NE / WFB)  // 4000 edges per wfill block
#define PREPB 64          // prep blocks
#define INPB ((NN + 31) / 32)

typedef _Float16 f16;
typedef _Float16 f16x8 __attribute__((ext_vector_type(8)));
typedef float f32x4 __attribute__((ext_vector_type(4)));

#define F2ADD(a, b) { (a).x += (b).x; (a).y += (b).y; }

__device__ __forceinline__ int waveInclScan(int v, int lane) {
#pragma unroll
    for (int o = 1; o < 64; o <<= 1) {
        int t = __shfl_up(v, o, 64);
        if (lane >= o) v += t;
    }
    return v;
}

// ---------------- prep: weight transposes + wcur init ----------------
__global__ __launch_bounds__(256) void k_prep_init(const float* __restrict__ Win,
                                                   const float* __restrict__ Wl,
                                                   const float* __restrict__ Wr,
                                                   const float* __restrict__ Wl2,
                                                   const float* __restrict__ Wr2,
                                                   const float* __restrict__ Wo1,
                                                   f16* __restrict__ WinT,
                                                   f16* __restrict__ W2T,
                                                   f16* __restrict__ W3T,
                                                   f16* __restrict__ Wo1T,
                                                   int* __restrict__ wcur) {
    int i0 = blockIdx.x * 256 + threadIdx.x;
    for (int i = i0; i < 128 * 104; i += PREPB * 256) {
        int c = i / 104, k = i - c * 104;
        float v = (k < 84) ? Win[k * 128 + c] : 0.f;
        WinT[c * 104 + k] = (f16)v;
    }
    for (int i = i0; i < 128 * 136; i += PREPB * 256) {
        int c = i / 136, k = i - c * 136;
        float v = 0.f;
        if (k < 128) v = (c < 64) ? Wl[k * 64 + c] : Wr[k * 64 + (c - 64)];
        W2T[c * 136 + k] = (f16)v;
    }
    for (int i = i0; i < 64 * 72; i += PREPB * 256) {
        int c = i / 72, k = i - c * 72;
        float v = 0.f;
        if (k < 64) v = (c < 32) ? Wl2[k * 32 + c] : Wr2[k * 32 + (c - 32)];
        W3T[c * 72 + k] = (f16)v;
    }
    for (int i = i0; i < 16 * 40; i += PREPB * 256) {
        int c = i / 40, k = i - c * 40;
        float v = (k < 32) ? Wo1[k * 16 + c] : 0.f;
        Wo1T[c * 40 + k] = (f16)v;
    }
    for (int i = i0; i < NW; i += PREPB * 256) wcur[i] = i * CAP;
}

// ---------------- fused: wfill (blocks <WFB) | MFMA in_proj1 (rest) ----------------
__global__ __launch_bounds__(256) void k_wfill_inproj(const int* __restrict__ src,
                                                      const int* __restrict__ tgt,
                                                      int* __restrict__ wcur,
                                                      int* __restrict__ colw,
                                                      const float* __restrict__ x,
                                                      const f16* __restrict__ WinT,
                                                      const float* __restrict__ bin,
                                                      const f16* __restrict__ W2T,
                                                      const float* __restrict__ bl,
                                                      f16* __restrict__ p1h,
                                                      f16* __restrict__ r1h, int N) {
    __shared__ int lh[NW];
    __shared__ int sb[NW];
    __shared__ __align__(16) f16 xs[32 * 104];
    __shared__ __align__(16) f16 hs[32 * 136];
    int tid = threadIdx.x;

    if (blockIdx.x < WFB) {
        // span-reserved window partition into CAP-strided colw
        int i4lo = (blockIdx.x * CHUNK) >> 2;
        int i4hi = i4lo + (CHUNK >> 2);
        for (int i = tid; i < NW; i += 256) lh[i] = 0;
        __syncthreads();
        for (int i4 = i4lo + tid; i4 < i4hi; i4 += 256) {
            int4 t = ((const int4*)tgt)[i4];
            atomicAdd(&lh[t.x >> 6], 1);
            atomicAdd(&lh[t.y >> 6], 1);
            atomicAdd(&lh[t.z >> 6], 1);
            atomicAdd(&lh[t.w >> 6], 1);
        }
        __syncthreads();
        for (int i = tid; i < NW; i += 256) {
            int c = lh[i];
            sb[i] = c ? atomicAdd(&wcur[i], c) : 0;
            lh[i] = 0;
        }
        __syncthreads();
        for (int i4 = i4lo + tid; i4 < i4hi; i4 += 256) {
            int4 t = ((const int4*)tgt)[i4];
            int4 s = ((const int4*)src)[i4];
            int w0 = t.x >> 6, r0 = atomicAdd(&lh[w0], 1);
            colw[sb[w0] + r0] = (s.x << 6) | (t.x & 63);
            int w1 = t.y >> 6, r1 = atomicAdd(&lh[w1], 1);
            colw[sb[w1] + r1] = (s.y << 6) | (t.y & 63);
            int w2 = t.z >> 6, r2 = atomicAdd(&lh[w2], 1);
            colw[sb[w2] + r2] = (s.z << 6) | (t.z & 63);
            int w3 = t.w >> 6, r3 = atomicAdd(&lh[w3], 1);
            colw[sb[w3] + r3] = (s.w << 6) | (t.w & 63);
        }
        return;
    }

    // ---- in_proj1: x -> h1 (LDS) -> p1, r1 via MFMA ----
    int node0 = (blockIdx.x - WFB) * 32;
    int lane = tid & 63;
    int wv = tid >> 6;
    int r = lane & 15;
    int q = lane >> 4;

    f16x8 b1[2][3];
#pragma unroll
    for (int nt = 0; nt < 2; nt++) {
        int c = (2 * wv + nt) * 16 + r;
#pragma unroll
        for (int ks = 0; ks < 3; ks++)
            b1[nt][ks] = *(const f16x8*)&WinT[c * 104 + ks * 32 + q * 8];
    }
    // float4-vectorized x staging
    for (int i = tid; i < 672; i += 256) {
        int nd = i / 21, k4 = i - nd * 21;
        int g = node0 + nd;
        float4 v = make_float4(0.f, 0.f, 0.f, 0.f);
        if (g < N) v = ((const float4*)x)[(size_t)g * 21 + k4];
        f16* dst = &xs[nd * 104 + k4 * 4];
        dst[0] = (f16)v.x; dst[1] = (f16)v.y; dst[2] = (f16)v.z; dst[3] = (f16)v.w;
    }
    for (int i = tid; i < 32 * 12; i += 256) {
        int nd = i / 12, k = 84 + (i - nd * 12);
        xs[nd * 104 + k] = (f16)0.f;
    }
    __syncthreads();

    f32x4 acc[2][2] = {};
#pragma unroll
    for (int ks = 0; ks < 3; ks++) {
        int k0 = ks * 32;
        f16x8 a[2];
#pragma unroll
        for (int mt = 0; mt < 2; mt++)
            a[mt] = *(const f16x8*)&xs[(mt * 16 + r) * 104 + k0 + q * 8];
#pragma unroll
        for (int mt = 0; mt < 2; mt++)
#pragma unroll
            for (int nt = 0; nt < 2; nt++)
                acc[mt][nt] = __builtin_amdgcn_mfma_f32_16x16x32_f16(a[mt], b1[nt][ks], acc[mt][nt], 0, 0, 0);
    }

    f16x8 b2[2][4];
#pragma unroll
    for (int nt = 0; nt < 2; nt++) {
        int c = (2 * wv + nt) * 16 + r;
#pragma unroll
        for (int ks = 0; ks < 4; ks++)
            b2[nt][ks] = *(const f16x8*)&W2T[c * 136 + ks * 32 + q * 8];
    }

#pragma unroll
    for (int nt = 0; nt < 2; nt++) {
        int c = (2 * wv + nt) * 16 + r;
        float bb = bin[c];
#pragma unroll
        for (int mt = 0; mt < 2; mt++)
#pragma unroll
            for (int v = 0; v < 4; v++) {
                int row = mt * 16 + q * 4 + v;
                float val = acc[mt][nt][v] + bb;
                hs[row * 136 + c] = (f16)(val > 0.f ? val : 0.f);
            }
    }
    __syncthreads();

    f32x4 acc2[2][2] = {};
#pragma unroll
    for (int ks = 0; ks < 4; ks++) {
        int k0 = ks * 32;
        f16x8 a[2];
#pragma unroll
        for (int mt = 0; mt < 2; mt++)
            a[mt] = *(const f16x8*)&hs[(mt * 16 + r) * 136 + k0 + q * 8];
#pragma unroll
        for (int mt = 0; mt < 2; mt++)
#pragma unroll
            for (int nt = 0; nt < 2; nt++)
                acc2[mt][nt] = __builtin_amdgcn_mfma_f32_16x16x32_f16(a[mt], b2[nt][ks], acc2[mt][nt], 0, 0, 0);
    }

    // epilogue 2: repack into hs (dead after GEMM2), then coalesced f16x8 stores
    __syncthreads();
#pragma unroll
    for (int nt = 0; nt < 2; nt++) {
        int c = (2 * wv + nt) * 16 + r;
        float bb = (c >= 64) ? bl[c - 64] : 0.f;
#pragma unroll
        for (int mt = 0; mt < 2; mt++)
#pragma unroll
            for (int v = 0; v < 4; v++) {
                int row = mt * 16 + q * 4 + v;
                hs[row * 136 + c] = (f16)(acc2[mt][nt][v] + bb);
            }
    }
    __syncthreads();
    {
        int row = tid >> 3, c8 = tid & 7;   // 32 rows x 8 chunks
        int n = node0 + row;
        if (n < N) {
            f16x8 vp = *(const f16x8*)&hs[row * 136 + c8 * 8];
            *(f16x8*)&p1h[(size_t)n * 64 + c8 * 8] = vp;
            f16x8 vr = *(const f16x8*)&hs[row * 136 + 64 + c8 * 8];
            *(f16x8*)&r1h[(size_t)n * 64 + c8 * 8] = vr;
        }
    }
}

// masked gather step: 4 loads per node (per-node math identical to R17)
#define GATH4(pv, STRIDE, LANE, s0, len, i, A0, A1, A2, A3)                          \
    {                                                                                \
        int i0_ = i, i1_ = i + 1, i2_ = i + 2, i3_ = i + 3;                          \
        unsigned x0_ = (i0_ < len) ? (unsigned)sorted[s0 + i0_] : 0u;                \
        unsigned x1_ = (i1_ < len) ? (unsigned)sorted[s0 + i1_] : 0u;                \
        unsigned x2_ = (i2_ < len) ? (unsigned)sorted[s0 + i2_] : 0u;                \
        unsigned x3_ = (i3_ < len) ? (unsigned)sorted[s0 + i3_] : 0u;                \
        float m0_ = (i0_ < len) ? 1.f : 0.f;                                         \
        float m1_ = (i1_ < len) ? 1.f : 0.f;                                         \
        float m2_ = (i2_ < len) ? 1.f : 0.f;                                         \
        float m3_ = (i3_ < len) ? 1.f : 0.f;                                         \
        float2 v0_ = __half22float2(pv[x0_ * STRIDE + LANE]);                        \
        float2 v1_ = __half22float2(pv[x1_ * STRIDE + LANE]);                        \
        float2 v2_ = __half22float2(pv[x2_ * STRIDE + LANE]);                        \
        float2 v3_ = __half22float2(pv[x3_ * STRIDE + LANE]);                        \
        A0.x += m0_ * v0_.x; A0.y += m0_ * v0_.y;                                    \
        A1.x += m1_ * v1_.x; A1.y += m1_ * v1_.y;                                    \
        A2.x += m2_ * v2_.x; A2.y += m2_ * v2_.y;                                    \
        A3.x += m3_ * v3_.x; A3.y += m3_ * v3_.y;                                    \
    }

// ---------------- agg1 (per-window, ONE 1024-thr block): LDS sort -> gather+LN -> MFMA proj2 ----------------
// Also exports the sorted src list (in-place into colw) + bucket counts for agg2.
__global__ __launch_bounds__(1024) void k_agg1_proj2(const __half2* __restrict__ p1v,
                                                     const __half2* __restrict__ r1v,
                                                     const int* __restrict__ wcur,
                                                     int* __restrict__ colw,
                                                     int* __restrict__ cnt64g,
                                                     const float* __restrict__ g1,
                                                     const float* __restrict__ be1,
                                                     const f16* __restrict__ W3T,
                                                     const float* __restrict__ bl2,
                                                     f16* __restrict__ p2h,
                                                     f16* __restrict__ r2h, int N) {
    __shared__ int cnt[64], start[64], cur[64];
    __shared__ int sorted[CAP];
    __shared__ __align__(16) f16 ys[64][72];
    int tid = threadIdx.x;
    int wb = blockIdx.x;
    int base = wb * CAP;
    int nb = wb << 6;
    int len = wcur[wb] - base;
    if (len > CAP) len = CAP;

    unsigned cc = tid & 31;
    int grp = tid >> 5;       // 32 groups of 32 lanes
    int lane = tid & 63;
    int wv = tid >> 6;        // 16 waves
    int r = lane & 15;
    int q = lane >> 4;

    // proj2 B-fragments: each of 16 waves owns one 16x16 output tile (mt, nt)
    int mt = wv & 3;
    int nt = wv >> 2;
    f16x8 b3[2];
#pragma unroll
    for (int ks = 0; ks < 2; ks++)
        b3[ks] = *(const f16x8*)&W3T[(nt * 16 + r) * 72 + ks * 32 + q * 8];

    // ---- per-window counting sort in LDS ----
    if (tid < 64) cnt[tid] = 0;
    __syncthreads();
    for (int i = tid; i < len; i += 1024) atomicAdd(&cnt[colw[base + i] & 63], 1);
    __syncthreads();
    if (tid < 64) {
        int v = cnt[tid];
        int incl = waveInclScan(v, tid);
        start[tid] = incl - v;
        cur[tid] = incl - v;
    }
    __syncthreads();
    for (int i = tid; i < len; i += 1024) {
        int pk = colw[base + i];
        int pos = atomicAdd(&cur[pk & 63], 1);
        sorted[pos] = pk >> 6;
    }
    __syncthreads();

    // export sorted list (in-place, own span) + counts for agg2; overlaps gather
    for (int i = tid; i < len; i += 1024) colw[base + i] = sorted[i];
    if (tid < 64) cnt64g[(wb << 6) + tid] = cnt[tid];

    // ---- paired gather + LN + relu: 2 nodes per 32-lane group ----
    {
        int tlA = grp;
        int tlB = grp + 32;
        int nA = nb + tlA, nB = nb + tlB;
        int lenA = (nA < N) ? cnt[tlA] : 0;
        int lenB = (nB < N) ? cnt[tlB] : 0;
        int s0A = start[tlA], s0B = start[tlB];
        int mx = lenA > lenB ? lenA : lenB;
        float2 aA0 = make_float2(0.f, 0.f), aA1 = aA0, aA2 = aA0, aA3 = aA0;
        float2 aB0 = aA0, aB1 = aA0, aB2 = aA0, aB3 = aA0;
        for (int i = 0; i < mx; i += 4) {
            GATH4(p1v, 32u, cc, s0A, lenA, i, aA0, aA1, aA2, aA3)
            GATH4(p1v, 32u, cc, s0B, lenB, i, aB0, aB1, aB2, aB3)
        }
        F2ADD(aA0, aA2) F2ADD(aA1, aA3) F2ADD(aA0, aA1)
        F2ADD(aB0, aB2) F2ADD(aB1, aB3) F2ADD(aB0, aB1)
#pragma unroll
        for (int sel = 0; sel < 2; sel++) {
            int tl = sel ? tlB : tlA;
            int n = sel ? nB : nA;
            int cntv = sel ? lenB : lenA;
            float2 ag = sel ? aB0 : aA0;
            if (n < N) {
                float inv = 1.f / (float)(cntv > 1 ? cntv : 1);
                float2 rr = __half22float2(r1v[(unsigned)n * 32u + cc]);
                float vx = ag.x * inv + rr.x;
                float vy = ag.y * inv + rr.y;
                float s = vx + vy;
#pragma unroll
                for (int o = 1; o < 32; o <<= 1) s += __shfl_xor(s, o, 32);
                float m = s * (1.f / 64.f);
                float dx = vx - m, dy = vy - m;
                float qv = dx * dx + dy * dy;
#pragma unroll
                for (int o = 1; o < 32; o <<= 1) qv += __shfl_xor(qv, o, 32);
                float rs = rsqrtf(qv * (1.f / 64.f) + EPS);
                float y0 = dx * rs * g1[2 * cc] + be1[2 * cc];
                float y1 = dy * rs * g1[2 * cc + 1] + be1[2 * cc + 1];
                ys[tl][2 * cc]     = (f16)(y0 > 0.f ? y0 : 0.f);
                ys[tl][2 * cc + 1] = (f16)(y1 > 0.f ? y1 : 0.f);
            } else {
                ys[tl][2 * cc] = (f16)0.f;
                ys[tl][2 * cc + 1] = (f16)0.f;
            }
        }
    }
    __syncthreads();

    // ---- proj2 via MFMA: [64 x 64] @ [64 x 64], one 16x16 tile per wave ----
    {
        f32x4 acc = {};
#pragma unroll
        for (int ks = 0; ks < 2; ks++) {
            f16x8 a = *(const f16x8*)&ys[mt * 16 + r][ks * 32 + q * 8];
            acc = __builtin_amdgcn_mfma_f32_16x16x32_f16(a, b3[ks], acc, 0, 0, 0);
        }
        int c2 = nt * 16 + r;
        float bb = (c2 >= 32) ? bl2[c2 - 32] : 0.f;
#pragma unroll
        for (int v = 0; v < 4; v++) {
            int n = nb + mt * 16 + q * 4 + v;
            if (n < N) {
                float val = acc[v];
                if (c2 < 32) p2h[(size_t)n * 32 + c2] = (f16)val;
                else         r2h[(size_t)n * 32 + (c2 - 32)] = (f16)(val + bb);
            }
        }
    }
}

// ---------------- agg2 (per-window, ONE 1024-thr block): reuse agg1's sorted list ----------------
__global__ __launch_bounds__(1024) void k_agg2_out(const __half2* __restrict__ p2v,
                                                   const __half2* __restrict__ r2v,
                                                   const int* __restrict__ wcur,
                                                   const int* __restrict__ colw,
                                                   const int* __restrict__ cnt64g,
                                                   const float* __restrict__ g2,
                                                   const float* __restrict__ be2,
                                                   const f16* __restrict__ Wo1T,
                                                   const float* __restrict__ bo1,
                                                   const float* __restrict__ Wo2,
                                                   const float* __restrict__ bo2,
                                                   float* __restrict__ out, int N) {
    __shared__ int cnt[64], start[64];
    __shared__ int sorted[CAP];
    __shared__ __align__(16) f16 ys[64][40];
    int tid = threadIdx.x;
    int wb = blockIdx.x;
    int base = wb * CAP;
    int nb = wb << 6;
    int len = wcur[wb] - base;
    if (len > CAP) len = CAP;

    unsigned l = tid & 15;
    int grp = tid >> 4;       // 64 groups of 16 lanes, one node each
    int lane = tid & 63;
    int wv = tid >> 6;        // 16 waves; waves 0..3 do the MFMA
    int r = lane & 15;
    int q = lane >> 4;

    f16x8 bo = *(const f16x8*)&Wo1T[r * 40 + q * 8];
    float b1v = bo1[r];
    float w2v = Wo2[r];

    // load counts + scan (no re-sort: colw already holds the sorted src list)
    if (tid < 64) {
        int v = cnt64g[(wb << 6) + tid];
        cnt[tid] = v;
        int incl = waveInclScan(v, tid);
        start[tid] = incl - v;
    }
    for (int i = tid; i < len; i += 1024) sorted[i] = colw[base + i];
    __syncthreads();

    // gather + LN + relu: one node per 16-lane group (masked 4-acc)
    {
        int tl = grp;
        int n = nb + tl;
        int lenA = (n < N) ? cnt[tl] : 0;
        int s0A = start[tl];
        float2 a0 = make_float2(0.f, 0.f), a1 = a0, a2 = a0, a3 = a0;
        for (int i = 0; i < lenA; i += 4) {
            GATH4(p2v, 16u, l, s0A, lenA, i, a0, a1, a2, a3)
        }
        F2ADD(a0, a2) F2ADD(a1, a3) F2ADD(a0, a1)
        if (n < N) {
            float inv = 1.f / (float)(lenA > 1 ? lenA : 1);
            float2 rr = __half22float2(r2v[(unsigned)n * 16u + l]);
            float vx = a0.x * inv + rr.x;
            float vy = a0.y * inv + rr.y;
            float s = vx + vy;
#pragma unroll
            for (int o = 1; o < 16; o <<= 1) s += __shfl_xor(s, o, 16);
            float m = s * (1.f / 32.f);
            float dx = vx - m, dy = vy - m;
            float qv = dx * dx + dy * dy;
#pragma unroll
            for (int o = 1; o < 16; o <<= 1) qv += __shfl_xor(qv, o, 16);
            float rs = rsqrtf(qv * (1.f / 32.f) + EPS);
            float y0 = dx * rs * g2[2 * l] + be2[2 * l];
            float y1 = dy * rs * g2[2 * l + 1] + be2[2 * l + 1];
            ys[tl][2 * l]     = (f16)(y0 > 0.f ? y0 : 0.f);
            ys[tl][2 * l + 1] = (f16)(y1 > 0.f ? y1 : 0.f);
        } else {
            ys[tl][2 * l] = (f16)0.f;
            ys[tl][2 * l + 1] = (f16)0.f;
        }
    }
    __syncthreads();

    // MLP: hidden = relu(y@Wo1+bo1) via MFMA, out = hidden@Wo2 + bo2 via reduce
    if (wv < 4) {
        f16x8 a = *(const f16x8*)&ys[wv * 16 + r][q * 8];
        f32x4 acc = {};
        acc = __builtin_amdgcn_mfma_f32_16x16x32_f16(a, bo, acc, 0, 0, 0);
#pragma unroll
        for (int v = 0; v < 4; v++) {
            float h = acc[v] + b1v;
            h = h > 0.f ? h : 0.f;
            float contrib = h * w2v;
#pragma unroll
            for (int o = 1; o < 16; o <<= 1) contrib += __shfl_xor(contrib, o, 16);
            int n = nb + wv * 16 + q * 4 + v;
            if (r == 0 && n < N) out[n] = contrib + bo2[0];
        }
    }
}

extern "C" void kernel_launch(void* const* d_in, const int* in_sizes, int n_in,
                              void* d_out, int out_size, void* d_ws, size_t ws_size,
                              hipStream_t stream) {
    const float* x    = (const float*)d_in[0];
    const int*   ei   = (const int*)d_in[1];
    const float* W_in = (const float*)d_in[2];
    const float* b_in = (const float*)d_in[3];
    const float* Wl1  = (const float*)d_in[4];
    const float* bl1  = (const float*)d_in[5];
    const float* Wr1  = (const float*)d_in[6];
    const float* g1   = (const float*)d_in[7];
    const float* be1  = (const float*)d_in[8];
    const float* Wl2  = (const float*)d_in[9];
    const float* bl2  = (const float*)d_in[10];
    const float* Wr2  = (const float*)d_in[11];
    const float* g2   = (const float*)d_in[12];
    const float* be2  = (const float*)d_in[13];
    const float* Wo1  = (const float*)d_in[14];
    const float* bo1  = (const float*)d_in[15];
    const float* Wo2  = (const float*)d_in[16];
    const float* bo2  = (const float*)d_in[17];
    float* out = (float*)d_out;

    const int N = NN, E = NE;
    const int* src = ei;
    const int* tgt = ei + E;

    // workspace layout
    char* w = (char*)d_ws;
    int* wcur   = (int*)w;  w += (size_t)NW * 4;
    w = (char*)(((uintptr_t)w + 15) & ~(uintptr_t)15);
    int* colw   = (int*)w;  w += (size_t)NW * CAP * 4;   // 8.0 MB, CAP-strided
    int* cnt64g = (int*)w;  w += (size_t)NW * 64 * 4;    // 200 KB
    f16* p1h  = (f16*)w;  w += (size_t)N * 64 * 2;
    f16* r1h  = (f16*)w;  w += (size_t)N * 64 * 2;
    f16* p2h  = (f16*)w;  w += (size_t)N * 32 * 2;
    f16* r2h  = (f16*)w;  w += (size_t)N * 32 * 2;
    f16* WinT = (f16*)w;  w += (size_t)128 * 104 * 2;
    f16* W2T  = (f16*)w;  w += (size_t)128 * 136 * 2;
    f16* W3T  = (f16*)w;  w += (size_t)64 * 72 * 2;
    f16* Wo1T = (f16*)w;  w += (size_t)16 * 40 * 2;

    // ---- 4-dispatch pipeline ----
    k_prep_init<<<PREPB, 256, 0, stream>>>(W_in, Wl1, Wr1, Wl2, Wr2, Wo1,
                                           WinT, W2T, W3T, Wo1T, wcur);
    k_wfill_inproj<<<WFB + INPB, 256, 0, stream>>>(src, tgt, wcur, colw,
                                                   x, WinT, b_in, W2T, bl1, p1h, r1h, N);
    k_agg1_proj2<<<NW, 1024, 0, stream>>>((const __half2*)p1h, (const __half2*)r1h,
                                          wcur, colw, cnt64g, g1, be1, W3T, bl2, p2h, r2h, N);
    k_agg2_out<<<NW, 1024, 0, stream>>>((const __half2*)p2h, (const __half2*)r2h,
                                        wcur, colw, cnt64g, g2, be2, Wo1T, bo1, Wo2, bo2, out, N);
}